// Round 3
// 460.551 us; speedup vs baseline: 1.0390x; 1.0390x over previous
//
#include <hip/hip_runtime.h>
#include <hip/hip_bf16.h>

#define PI_F 3.14159265358979323846f

// clang ext_vector_type: __builtin_nontemporal_store requires a pointer to a
// builtin scalar/vector type (HIP's float2 class is NOT accepted).
typedef float f32x2 __attribute__((ext_vector_type(2)));

// ---------------------------------------------------------------------------
// Kernel 1: per-batch matrix build + analytic 3x3 (affine) inverse.
// mat = trn @ shr @ scl @ rot collapsed analytically:
//   m00 = sx*c + shxy*sy*s ; m01 = -sx*s + shxy*sy*c ; m02 = tx
//   m10 = shyx*sx*c + sy*s ; m11 = -shyx*sx*s + sy*c ; m12 = ty
//   row2 = [0,0,1]
// ---------------------------------------------------------------------------
__global__ void build_mats_kernel(const float* __restrict__ fc2,
                                  float* __restrict__ mat_out,
                                  float* __restrict__ inv_out,
                                  int B) {
    int b = blockIdx.x * blockDim.x + threadIdx.x;
    if (b >= B) return;
    const float* f = fc2 + b * 7;
    float theta = fminf(fmaxf(f[0] * 0.3f, -1.f), 1.f) * PI_F;
    float sx    = fminf(fmaxf(f[1] * 0.3f + 1.f, 0.f), 5.f);
    float sy    = fminf(fmaxf(f[2] * 0.3f + 1.f, 0.f), 5.f);
    float tx    = f[3] * 0.3f;
    float ty    = f[4] * 0.3f;
    float shxy  = fminf(fmaxf(f[5] * 0.3f, -1.f), 1.f) * PI_F;
    float shyx  = fminf(fmaxf(f[6] * 0.3f, -1.f), 1.f) * PI_F;

    float c = cosf(theta), s = sinf(theta);
    float m00 =  sx * c + shxy * sy * s;
    float m01 = -sx * s + shxy * sy * c;
    float m02 = tx;
    float m10 = shyx * sx * c + sy * s;
    float m11 = -shyx * sx * s + sy * c;
    float m12 = ty;

    float* m = mat_out + b * 9;
    m[0] = m00; m[1] = m01; m[2] = m02;
    m[3] = m10; m[4] = m11; m[5] = m12;
    m[6] = 0.f; m[7] = 0.f; m[8] = 1.f;

    // Affine inverse: [[A^-1, -A^-1 t],[0,0,1]]
    float det = m00 * m11 - m01 * m10;
    float id  = 1.f / det;
    float i00 =  m11 * id, i01 = -m01 * id;
    float i10 = -m10 * id, i11 =  m00 * id;
    float i02 = -(i00 * m02 + i01 * m12);
    float i12 = -(i10 * m02 + i11 * m12);

    float* im = inv_out + b * 9;
    im[0] = i00; im[1] = i01; im[2] = i02;
    im[3] = i10; im[4] = i11; im[5] = i12;
    im[6] = 0.f; im[7] = 0.f; im[8] = 1.f;
}

// ---------------------------------------------------------------------------
// Kernel 2: 2-D tiled. blockDim=(8,8,4): each wave (z-slice) owns an 8x8
// pixel tile; the 4 waves tile a 16x16 block region (2x2 subtiles).
// Rationale: with a 1x256 strip, a rotated transform makes the 64 lanes of a
// wave span ~64*|m10| src ROWS, so every gather load touches up to 64 cache
// lines (~1000 L1 transactions/wave == measured 213us). An 8x8 wave footprint
// is a compact ~11x11 px parallelogram for ANY rotation: ~24 lines/load, and
// the block's ~8KB src footprint lives in L1 across the 4 taps / 4 channels.
// Stores stay coalesced: each wave row = one full aligned 64B line of
// grid/inv_grid (nontemporal: pure streaming, never re-read); transformed
// rows are 32B halves merged in L2 by the adjacent subtile's wave.
// ---------------------------------------------------------------------------
__global__ __launch_bounds__(256) void affine_main_kernel(
    const float* __restrict__ src,
    const float* __restrict__ mat,
    const float* __restrict__ inv_mat,
    float* __restrict__ transformed,
    float* __restrict__ grid_out,
    float* __restrict__ inv_grid_out)
{
    const int W = 512, H = 512, C = 4;
    const int tx = threadIdx.x;           // 0..7
    const int ty = threadIdx.y;           // 0..7
    const int tz = threadIdx.z;           // 0..3 -> 2x2 subtile
    const int w = blockIdx.x * 16 + (tz & 1) * 8 + tx;
    const int h = blockIdx.y * 16 + (tz >> 1) * 8 + ty;
    const int b = blockIdx.z;

    float xs = (2.f * (float)w + 1.f) * (1.f / (float)W) - 1.f;
    float ys = (2.f * (float)h + 1.f) * (1.f / (float)H) - 1.f;

    const float* m  = mat + b * 9;        // b wave-uniform -> scalar loads
    const float* im = inv_mat + b * 9;
    float gx  = m[0] * xs + m[1] * ys + m[2];
    float gy  = m[3] * xs + m[4] * ys + m[5];
    float igx = im[0] * xs + im[1] * ys + im[2];
    float igy = im[3] * xs + im[4] * ys + im[5];

    size_t pix = ((size_t)b * H + h) * W + w;
    f32x2 g2  = {gx, gy};
    f32x2 ig2 = {igx, igy};
    __builtin_nontemporal_store(g2,  (f32x2*)grid_out + pix);
    __builtin_nontemporal_store(ig2, (f32x2*)inv_grid_out + pix);

    // Bilinear sample (align_corners=False convention per reference)
    float ix = ((gx + 1.f) * (float)W - 1.f) * 0.5f;
    float iy = ((gy + 1.f) * (float)H - 1.f) * 0.5f;
    float x0f = floorf(ix), y0f = floorf(iy);
    float wx = ix - x0f, wy = iy - y0f;
    int x0 = (int)x0f, y0 = (int)y0f;
    int x1 = x0 + 1,   y1 = y0 + 1;

    bool vx0 = (x0 >= 0) && (x0 < W);
    bool vx1 = (x1 >= 0) && (x1 < W);
    bool vy0 = (y0 >= 0) && (y0 < H);
    bool vy1 = (y1 >= 0) && (y1 < H);
    int cx0 = min(max(x0, 0), W - 1), cx1 = min(max(x1, 0), W - 1);
    int cy0 = min(max(y0, 0), H - 1), cy1 = min(max(y1, 0), H - 1);

    float w00 = (1.f - wx) * (1.f - wy) * ((vx0 && vy0) ? 1.f : 0.f);
    float w01 = wx * (1.f - wy)         * ((vx1 && vy0) ? 1.f : 0.f);
    float w10 = (1.f - wx) * wy         * ((vx0 && vy1) ? 1.f : 0.f);
    float w11 = wx * wy                 * ((vx1 && vy1) ? 1.f : 0.f);

    const float* sb = src + (size_t)b * C * H * W;
    // 32-bit offsets: per-batch plane is 4*512*512 floats < 2^31
    int o00 = cy0 * W + cx0;
    int o01 = cy0 * W + cx1;
    int o10 = cy1 * W + cx0;
    int o11 = cy1 * W + cx1;

    #pragma unroll
    for (int c = 0; c < C; ++c) {
        const float* sc = sb + c * (H * W);
        float v = sc[o00] * w00 + sc[o01] * w01 + sc[o10] * w10 + sc[o11] * w11;
        transformed[(((size_t)b * C + c) * H + h) * W + w] = v;
    }
}

extern "C" void kernel_launch(void* const* d_in, const int* in_sizes, int n_in,
                              void* d_out, int out_size, void* d_ws, size_t ws_size,
                              hipStream_t stream) {
    const float* src = (const float*)d_in[0];   // (32,4,512,512) f32
    const float* fc2 = (const float*)d_in[1];   // (32,7) f32

    const int B = 32, C = 4, H = 512, W = 512;
    float* out = (float*)d_out;

    // Output layout (flat, return order):
    float* transformed  = out;                                   // 33,554,432
    float* mat_out      = out + (size_t)B * C * H * W;           // +288
    float* inv_out      = mat_out + (size_t)B * 9;               // +288
    float* grid_out     = inv_out + (size_t)B * 9;               // +16,777,216
    float* inv_grid_out = grid_out + (size_t)B * H * W * 2;      // +16,777,216

    // Kernel 1: 32 matrices
    build_mats_kernel<<<1, 64, 0, stream>>>(fc2, mat_out, inv_out, B);

    // Kernel 2: per-pixel grids + bilinear sampling, 16x16 tiles
    dim3 grid(W / 16, H / 16, B);
    dim3 block(8, 8, 4);
    affine_main_kernel<<<grid, block, 0, stream>>>(src, mat_out, inv_out,
                                                   transformed, grid_out, inv_grid_out);
}

// Round 4
// 445.744 us; speedup vs baseline: 1.0735x; 1.0332x over previous
//
#include <hip/hip_runtime.h>

#define PI_F 3.14159265358979323846f

// clang ext_vector_type: __builtin_nontemporal_store requires a pointer to a
// builtin scalar/vector type (HIP's float2/float4 classes are NOT accepted).
typedef float f32x4 __attribute__((ext_vector_type(4)));

// ---------------------------------------------------------------------------
// Kernel 1: per-batch matrix build + analytic 3x3 (affine) inverse.
// mat = trn @ shr @ scl @ rot collapsed analytically:
//   m00 = sx*c + shxy*sy*s ; m01 = -sx*s + shxy*sy*c ; m02 = tx
//   m10 = shyx*sx*c + sy*s ; m11 = -shyx*sx*s + sy*c ; m12 = ty
// ---------------------------------------------------------------------------
__global__ void build_mats_kernel(const float* __restrict__ fc2,
                                  float* __restrict__ mat_out,
                                  float* __restrict__ inv_out,
                                  int B) {
    int b = blockIdx.x * blockDim.x + threadIdx.x;
    if (b >= B) return;
    const float* f = fc2 + b * 7;
    float theta = fminf(fmaxf(f[0] * 0.3f, -1.f), 1.f) * PI_F;
    float sx    = fminf(fmaxf(f[1] * 0.3f + 1.f, 0.f), 5.f);
    float sy    = fminf(fmaxf(f[2] * 0.3f + 1.f, 0.f), 5.f);
    float tx    = f[3] * 0.3f;
    float ty    = f[4] * 0.3f;
    float shxy  = fminf(fmaxf(f[5] * 0.3f, -1.f), 1.f) * PI_F;
    float shyx  = fminf(fmaxf(f[6] * 0.3f, -1.f), 1.f) * PI_F;

    float c = cosf(theta), s = sinf(theta);
    float m00 =  sx * c + shxy * sy * s;
    float m01 = -sx * s + shxy * sy * c;
    float m02 = tx;
    float m10 = shyx * sx * c + sy * s;
    float m11 = -shyx * sx * s + sy * c;
    float m12 = ty;

    float* m = mat_out + b * 9;
    m[0] = m00; m[1] = m01; m[2] = m02;
    m[3] = m10; m[4] = m11; m[5] = m12;
    m[6] = 0.f; m[7] = 0.f; m[8] = 1.f;

    // Affine inverse: [[A^-1, -A^-1 t],[0,0,1]]
    float det = m00 * m11 - m01 * m10;
    float id  = 1.f / det;
    float i00 =  m11 * id, i01 = -m01 * id;
    float i10 = -m10 * id, i11 =  m00 * id;
    float i02 = -(i00 * m02 + i01 * m12);
    float i12 = -(i10 * m02 + i11 * m12);

    float* im = inv_out + b * 9;
    im[0] = i00; im[1] = i01; im[2] = i02;
    im[3] = i10; im[4] = i11; im[5] = i12;
    im[6] = 0.f; im[7] = 0.f; im[8] = 1.f;
}

// ---------------------------------------------------------------------------
// Kernel 2: PURE STREAMING grid writer. One block = one row (h=blockIdx.x)
// of one batch (b=blockIdx.y, wave-uniform -> s_load of the matrices).
// Each thread computes 2 pixels and writes one 16B f32x4 to grid and one to
// inv_grid (nontemporal: never re-read). Per wave: 1KB contiguous per
// stream -> full-line writes. This kernel should run at the write-BW
// ceiling; if it doesn't, the write path itself is the systemic limiter.
// ---------------------------------------------------------------------------
__global__ __launch_bounds__(256) void grid_kernel(
    const float* __restrict__ mat,
    const float* __restrict__ inv_mat,
    float* __restrict__ grid_out,
    float* __restrict__ inv_grid_out)
{
    const int W = 512, H = 512;
    const int h = blockIdx.x;
    const int b = blockIdx.y;
    const int w = threadIdx.x * 2;

    float xs0 = (2.f * (float)w + 1.f) * (1.f / (float)W) - 1.f;
    float xs1 = xs0 + 2.f / (float)W;
    float ys  = (2.f * (float)h + 1.f) * (1.f / (float)H) - 1.f;

    const float* m  = mat + b * 9;       // uniform -> scalar loads
    const float* im = inv_mat + b * 9;

    // Same association as reference/sampler: m0*xs + (m1*ys + m2)
    float gx0  = m[0] * xs0 + (m[1] * ys + m[2]);
    float gy0  = m[3] * xs0 + (m[4] * ys + m[5]);
    float gx1  = m[0] * xs1 + (m[1] * ys + m[2]);
    float gy1  = m[3] * xs1 + (m[4] * ys + m[5]);
    float igx0 = im[0] * xs0 + (im[1] * ys + im[2]);
    float igy0 = im[3] * xs0 + (im[4] * ys + im[5]);
    float igx1 = im[0] * xs1 + (im[1] * ys + im[2]);
    float igy1 = im[3] * xs1 + (im[4] * ys + im[5]);

    size_t vec = ((size_t)b * H + h) * (W / 2) + threadIdx.x;  // f32x4 index
    f32x4 g  = {gx0, gy0, gx1, gy1};
    f32x4 ig = {igx0, igy0, igx1, igy1};
    __builtin_nontemporal_store(g,  (f32x4*)grid_out + vec);
    __builtin_nontemporal_store(ig, (f32x4*)inv_grid_out + vec);
}

// ---------------------------------------------------------------------------
// Kernel 3: GATHER-ONLY sampler. Recomputes gx,gy (2 FMA — cheaper than
// re-reading grid) and bilinear-samples 4 channels. Wave = 16x4 px tile so
// every transformed row-store is a FULL aligned 64B line (nontemporal);
// 4 waves stack to a 16x16 block region keeping the src footprint compact
// (~20x7 px parallelogram per wave for any rotation). inv_mat not needed.
// ---------------------------------------------------------------------------
__global__ __launch_bounds__(256) void sample_kernel(
    const float* __restrict__ src,
    const float* __restrict__ mat,
    float* __restrict__ transformed)
{
    const int W = 512, H = 512, C = 4;
    const int w = blockIdx.x * 16 + threadIdx.x;               // 16 wide
    const int h = blockIdx.y * 16 + threadIdx.z * 4 + threadIdx.y;
    const int b = blockIdx.z;

    float xs = (2.f * (float)w + 1.f) * (1.f / (float)W) - 1.f;
    float ys = (2.f * (float)h + 1.f) * (1.f / (float)H) - 1.f;

    const float* m = mat + b * 9;        // blockIdx.z uniform -> s_load
    float gx = m[0] * xs + (m[1] * ys + m[2]);
    float gy = m[3] * xs + (m[4] * ys + m[5]);

    // Bilinear sample (align_corners=False convention per reference)
    float ix = ((gx + 1.f) * (float)W - 1.f) * 0.5f;
    float iy = ((gy + 1.f) * (float)H - 1.f) * 0.5f;
    float x0f = floorf(ix), y0f = floorf(iy);
    float wx = ix - x0f, wy = iy - y0f;
    int x0 = (int)x0f, y0 = (int)y0f;
    int x1 = x0 + 1,   y1 = y0 + 1;

    bool vx0 = (x0 >= 0) && (x0 < W);
    bool vx1 = (x1 >= 0) && (x1 < W);
    bool vy0 = (y0 >= 0) && (y0 < H);
    bool vy1 = (y1 >= 0) && (y1 < H);
    int cx0 = min(max(x0, 0), W - 1), cx1 = min(max(x1, 0), W - 1);
    int cy0 = min(max(y0, 0), H - 1), cy1 = min(max(y1, 0), H - 1);

    float w00 = (1.f - wx) * (1.f - wy) * ((vx0 && vy0) ? 1.f : 0.f);
    float w01 = wx * (1.f - wy)         * ((vx1 && vy0) ? 1.f : 0.f);
    float w10 = (1.f - wx) * wy         * ((vx0 && vy1) ? 1.f : 0.f);
    float w11 = wx * wy                 * ((vx1 && vy1) ? 1.f : 0.f);

    const float* sb = src + (size_t)b * C * H * W;
    // 32-bit offsets: per-batch plane is 4*512*512 floats < 2^31
    int o00 = cy0 * W + cx0;
    int o01 = cy0 * W + cx1;
    int o10 = cy1 * W + cx0;
    int o11 = cy1 * W + cx1;

    #pragma unroll
    for (int c = 0; c < C; ++c) {
        const float* sc = sb + c * (H * W);
        float v = sc[o00] * w00 + sc[o01] * w01 + sc[o10] * w10 + sc[o11] * w11;
        __builtin_nontemporal_store(
            v, transformed + (((size_t)b * C + c) * H + h) * W + w);
    }
}

extern "C" void kernel_launch(void* const* d_in, const int* in_sizes, int n_in,
                              void* d_out, int out_size, void* d_ws, size_t ws_size,
                              hipStream_t stream) {
    const float* src = (const float*)d_in[0];   // (32,4,512,512) f32
    const float* fc2 = (const float*)d_in[1];   // (32,7) f32

    const int B = 32, C = 4, H = 512, W = 512;
    float* out = (float*)d_out;

    // Output layout (flat, return order):
    float* transformed  = out;                                   // 33,554,432
    float* mat_out      = out + (size_t)B * C * H * W;           // +288
    float* inv_out      = mat_out + (size_t)B * 9;               // +288
    float* grid_out     = inv_out + (size_t)B * 9;               // +16,777,216
    float* inv_grid_out = grid_out + (size_t)B * H * W * 2;      // +16,777,216

    // Kernel 1: 32 matrices
    build_mats_kernel<<<1, 64, 0, stream>>>(fc2, mat_out, inv_out, B);

    // Kernel 2: pure-streaming grid + inv_grid writer (one row per block)
    grid_kernel<<<dim3(H, B), 256, 0, stream>>>(mat_out, inv_out,
                                                grid_out, inv_grid_out);

    // Kernel 3: gather-only bilinear sampler, 16x16 tiles, 16x4 waves
    sample_kernel<<<dim3(W / 16, H / 16, B), dim3(16, 4, 4), 0, stream>>>(
        src, mat_out, transformed);
}